// Round 3
// baseline (11970.296 us; speedup 1.0000x reference)
//
#include <hip/hip_runtime.h>
#include <hip/hip_cooperative_groups.h>
#include <stdint.h>

namespace cg = cooperative_groups;

typedef unsigned short u16;
typedef __attribute__((ext_vector_type(8))) _Float16 f16x8;
typedef __attribute__((ext_vector_type(4))) float f32x4;

// ---------- helpers ----------
__device__ inline f16x8 ldfrag(const u16* p) { return *(const f16x8*)p; }
__device__ inline u16 f2h(float x) {
    _Float16 h = (_Float16)x;
    union { _Float16 h; u16 u; } v; v.h = h;
    return v.u;
}
__device__ inline float sigmoidf_(float x) { return 1.0f / (1.0f + expf(-x)); }

// Layouts (fp16 as u16):
//  A-frag (X: 256 x K):  AF[mtile][kb][lane][8]
//      = X[mtile*16 + (lane&15)][kb*32 + (lane>>4)*8 + j]
//  B-frag (W: N x K):    BF[grp][sub][kb][lane][8]
//      = W[row(grp,sub,lane)][kb*32 + (lane>>4)*8 + j],  row = sub*S1 + grp*S2 + (lane&15)
//  lstm:  S1=1024 (gate), S2=16 (ct)   -> BF[ct][gate][kb][..]
//  fc1:   S1=16,  S2=64                -> BF[ctq][nt ][kb][..]
//  fc2:   S1=16,  S2=0 (grp=0)         -> BF[0][nt][kb][..]

struct PP {
    const u16* xyenc;
    u16* xdec;
    const u16 *wih0, *whh0, *wih1, *whh1, *fcw1, *fcw2;
    const float *b0s, *b1s, *fcb1, *fcb2, *pre_y;
    u16 *h0a, *h0b, *h1a, *h1b, *ufc;
    float* out;
};

// ---------- LSTM cell phase (per-block role: ct = b&63, mg = b>>6) ----------
// 512 threads = 8 waves, 8-way K-split; two-stage LDS reduction; c-state in regs.
static __device__ __forceinline__ void lstm_phase(
    const u16* __restrict__ AFa, int KBa, const u16* __restrict__ BFa,
    const u16* __restrict__ AFh, const u16* __restrict__ BFh,
    const float* __restrict__ bsum, float* creg, u16* __restrict__ h_out,
    int ct, int mg, int w, int lane, f32x4 (*red)[16][64])
{
    const int l15  = lane & 15;
    const int quad = lane >> 4;

    f32x4 acc[4][4];
    #pragma unroll
    for (int t = 0; t < 4; ++t)
        #pragma unroll
        for (int g = 0; g < 4; ++g) acc[t][g] = (f32x4){0, 0, 0, 0};

    // phase A: x-side, wave w takes kb in [w*q, w*q+q), q = KBa/8
    {
        const int q = KBa >> 3;
        #pragma unroll 2
        for (int kb = w * q; kb < w * q + q; ++kb) {
            f16x8 a[4], b[4];
            #pragma unroll
            for (int t = 0; t < 4; ++t)
                a[t] = ldfrag(AFa + (((size_t)(mg * 4 + t) * KBa + kb) * 64 + lane) * 8);
            #pragma unroll
            for (int g = 0; g < 4; ++g)
                b[g] = ldfrag(BFa + (((size_t)(ct * 4 + g) * KBa + kb) * 64 + lane) * 8);
            #pragma unroll
            for (int t = 0; t < 4; ++t)
                #pragma unroll
                for (int g = 0; g < 4; ++g)
                    acc[t][g] = __builtin_amdgcn_mfma_f32_16x16x32_f16(a[t], b[g], acc[t][g], 0, 0, 0);
        }
    }
    // phase B: h-side, KB=32, eighth = 4
    {
        #pragma unroll 2
        for (int kb = w * 4; kb < w * 4 + 4; ++kb) {
            f16x8 a[4], b[4];
            #pragma unroll
            for (int t = 0; t < 4; ++t)
                a[t] = ldfrag(AFh + (((size_t)(mg * 4 + t) * 32 + kb) * 64 + lane) * 8);
            #pragma unroll
            for (int g = 0; g < 4; ++g)
                b[g] = ldfrag(BFh + (((size_t)(ct * 4 + g) * 32 + kb) * 64 + lane) * 8);
            #pragma unroll
            for (int t = 0; t < 4; ++t)
                #pragma unroll
                for (int g = 0; g < 4; ++g)
                    acc[t][g] = __builtin_amdgcn_mfma_f32_16x16x32_f16(a[t], b[g], acc[t][g], 0, 0, 0);
        }
    }

    // two-stage cross-wave K-reduction (8 partials -> 4 -> sum)
    if (w >= 4) {
        #pragma unroll
        for (int t = 0; t < 4; ++t)
            #pragma unroll
            for (int g = 0; g < 4; ++g)
                red[w - 4][t * 4 + g][lane] = acc[t][g];
    }
    __syncthreads();
    if (w < 4) {
        #pragma unroll
        for (int t = 0; t < 4; ++t)
            #pragma unroll
            for (int g = 0; g < 4; ++g)
                red[w][t * 4 + g][lane] += acc[t][g];
    }
    __syncthreads();
    if (w < 4) {
        // wave w owns mt = mg*4 + w
        f32x4 z[4];
        #pragma unroll
        for (int g = 0; g < 4; ++g)
            z[g] = red[0][w * 4 + g][lane] + red[1][w * 4 + g][lane] +
                   red[2][w * 4 + g][lane] + red[3][w * 4 + g][lane];

        const int col   = ct * 16 + l15;
        const int mtile = mg * 4 + w;
        float bv[4];
        #pragma unroll
        for (int g = 0; g < 4; ++g) bv[g] = bsum[g * 1024 + col];
        const int hkb = col >> 5, hquad = (col >> 3) & 3, hj = col & 7;
        #pragma unroll
        for (int r = 0; r < 4; ++r) {
            const int rl = quad * 4 + r;
            const float zi = z[0][r] + bv[0];
            const float zf = z[1][r] + bv[1];
            const float zg = z[2][r] + bv[2];
            const float zo = z[3][r] + bv[3];
            const float cv = creg[r];
            const float cn = sigmoidf_(zf) * cv + sigmoidf_(zi) * tanhf(zg);
            creg[r] = cn;
            h_out[(((size_t)mtile * 32 + hkb) * 64 + hquad * 16 + rl) * 8 + hj] =
                f2h(sigmoidf_(zo) * tanhf(cn));
        }
    }
}

// ---------- FC1 phase: U = tanh(h1 @ fc_w1^T + b1) ----------
// 256 blocks: mt = b>>4 (0..15), ctq = b&15; 8 waves 8-way K-split.
static __device__ __forceinline__ void fc1_phase(
    const u16* __restrict__ AFx, const u16* __restrict__ BFw,
    const float* __restrict__ bias, u16* __restrict__ U,
    int b, int w, int lane, f32x4 (*red)[16][64])
{
    const int mt = b >> 4, ctq = b & 15;
    const int l15 = lane & 15, quad = lane >> 4;
    f32x4 acc[4];
    #pragma unroll
    for (int g = 0; g < 4; ++g) acc[g] = (f32x4){0, 0, 0, 0};

    #pragma unroll
    for (int k = 0; k < 4; ++k) {
        const int kb = w * 4 + k;
        f16x8 a = ldfrag(AFx + (((size_t)mt * 32 + kb) * 64 + lane) * 8);
        #pragma unroll
        for (int g = 0; g < 4; ++g) {
            f16x8 bb = ldfrag(BFw + (((size_t)(ctq * 4 + g) * 32 + kb) * 64 + lane) * 8);
            acc[g] = __builtin_amdgcn_mfma_f32_16x16x32_f16(a, bb, acc[g], 0, 0, 0);
        }
    }

    f32x4 (*r8)[4][64] = (f32x4 (*)[4][64])red;   // [8][4][64]
    #pragma unroll
    for (int g = 0; g < 4; ++g) r8[w][g][lane] = acc[g];
    __syncthreads();
    if (w < 4) {
        f32x4 z = r8[0][w][lane];
        #pragma unroll
        for (int p = 1; p < 8; ++p) z += r8[p][w][lane];
        const int col = ctq * 64 + w * 16 + l15;
        const float bv = bias[col];
        const int ukb = col >> 5, uq = (col >> 3) & 3, uj = col & 7;
        #pragma unroll
        for (int r = 0; r < 4; ++r) {
            const int rl = quad * 4 + r;
            U[(((size_t)mt * 32 + ukb) * 64 + uq * 16 + rl) * 8 + uj] =
                f2h(tanhf(z[r] + bv));
        }
    }
}

// ---------- FC2 phase + est feedback (blocks b<64: mt = b>>2, cg = b&3) ----------
static __device__ __forceinline__ void fc2_phase(
    const u16* __restrict__ AFu, const u16* __restrict__ BFw2,
    const float* __restrict__ b2, float* estreg,
    float* __restrict__ out_t, u16* __restrict__ xdec_t,
    int b, int w, int lane, f32x4 (*red)[16][64])
{
    f32x4 (*rr)[64] = (f32x4 (*)[64])red;   // [8][64]
    const int l15 = lane & 15, quad = lane >> 4;
    const int mt = b >> 2, cg = b & 3;
    if (b < 64) {
        f32x4 acc = (f32x4){0, 0, 0, 0};
        #pragma unroll
        for (int k = 0; k < 4; ++k) {
            const int kb = w * 4 + k;
            acc = __builtin_amdgcn_mfma_f32_16x16x32_f16(
                ldfrag(AFu + (((size_t)mt * 32 + kb) * 64 + lane) * 8),
                ldfrag(BFw2 + (((size_t)cg * 32 + kb) * 64 + lane) * 8), acc, 0, 0, 0);
        }
        rr[w][lane] = acc;
    }
    __syncthreads();
    if (b < 64 && w == 0) {
        f32x4 acc = rr[0][lane];
        #pragma unroll
        for (int p = 1; p < 8; ++p) acc += rr[p][lane];
        const int col = cg * 16 + l15;
        const float bv = b2[col];
        const int cx = 192 + col;
        const int xkb = cx >> 5, xq = (cx >> 3) & 3, xj = cx & 7;
        #pragma unroll
        for (int r = 0; r < 4; ++r) {
            const int rl = quad * 4 + r;
            const int row = mt * 16 + rl;
            const float v = acc[r] + bv + estreg[r];
            estreg[r] = v;
            out_t[row * 64 + col] = v;
            xdec_t[(((size_t)mt * 8 + xkb) * 64 + xq * 16 + rl) * 8 + xj] = f2h(v);
        }
    }
}

// ---------- persistent cooperative kernel: whole recurrence ----------
__global__ __launch_bounds__(512, 2) void persist_k(PP p)
{
    cg::grid_group grid = cg::this_grid();
    __shared__ f32x4 red[4][16][64];   // 64 KB, reused by every phase

    const int tid  = threadIdx.x;
    const int w    = tid >> 6;
    const int lane = tid & 63;
    const int l15  = lane & 15;
    const int quad = lane >> 4;
    const int b    = blockIdx.x;       // 0..255
    const int ct   = b & 63;
    const int mg   = b >> 6;

    // persistent per-thread state
    float c0reg[4] = {0.f, 0.f, 0.f, 0.f};
    float c1reg[4] = {0.f, 0.f, 0.f, 0.f};
    float estreg[4] = {0.f, 0.f, 0.f, 0.f};
    if (b < 64) {   // only fc2-active blocks own est state (row = (b>>2)*16+..., col = (b&3)*16+...)
        const int fmt = b >> 2, fcg = b & 3;
        #pragma unroll
        for (int r = 0; r < 4; ++r) {
            const int row = fmt * 16 + quad * 4 + r;
            const int col = fcg * 16 + l15;
            estreg[r] = p.pre_y[(size_t)63 * 16384 + row * 64 + col];  // pre_y[-1]
        }
    }

    u16 *h0c = p.h0a, *h0n = p.h0b;
    u16 *h1c = p.h1a, *h1n = p.h1b;

    // --- encode: 64 steps, 2 grid syncs each ---
    for (int t = 0; t < 64; ++t) {
        lstm_phase(p.xyenc + (size_t)t * 65536, 8, p.wih0, h0c, p.whh0,
                   p.b0s, c0reg, h0n, ct, mg, w, lane, red);
        grid.sync();
        lstm_phase(h0n, 32, p.wih1, h1c, p.whh1,
                   p.b1s, c1reg, h1n, ct, mg, w, lane, red);
        grid.sync();
        u16* tmp;
        tmp = h0c; h0c = h0n; h0n = tmp;
        tmp = h1c; h1c = h1n; h1n = tmp;
    }

    // --- decode: 48 steps; last step needs only fc1+fc2 ---
    for (int t = 0; t < 48; ++t) {
        fc1_phase(h1c, p.fcw1, p.fcb1, p.ufc, b, w, lane, red);
        grid.sync();
        fc2_phase(p.ufc, p.fcw2, p.fcb2, estreg,
                  p.out + (size_t)t * 16384, p.xdec + (size_t)t * 65536,
                  b, w, lane, red);
        grid.sync();
        if (t < 47) {
            lstm_phase(p.xdec + (size_t)t * 65536, 8, p.wih0, h0c, p.whh0,
                       p.b0s, c0reg, h0n, ct, mg, w, lane, red);
            grid.sync();
            lstm_phase(h0n, 32, p.wih1, h1c, p.whh1,
                       p.b1s, c1reg, h1n, ct, mg, w, lane, red);
            grid.sync();
            u16* tmp;
            tmp = h0c; h0c = h0n; h0n = tmp;
            tmp = h1c; h1c = h1n; h1n = tmp;
        }
    }
}

// ---------- setup kernels ----------
__global__ void cvt_bfrag_k(const float* __restrict__ src, u16* __restrict__ dst,
                            int K, int kbshift, int S1, int S2, int total) {
    int i = blockIdx.x * 256 + threadIdx.x;
    if (i >= total) return;
    const int lane = i & 63;
    const int kb   = (i >> 6) & ((1 << kbshift) - 1);
    const int rest = i >> (6 + kbshift);
    const int sub  = rest & 3;
    const int grp  = rest >> 2;
    const int row  = sub * S1 + grp * S2 + (lane & 15);
    const int colK = kb * 32 + (lane >> 4) * 8;
    const float* s = src + (size_t)row * K + colK;
    u16* d = dst + (size_t)i * 8;
    #pragma unroll
    for (int j = 0; j < 8; ++j) d[j] = f2h(s[j]);
}
__global__ void bias_k(const float* __restrict__ a, const float* __restrict__ b,
                       float* __restrict__ d, int n) {
    int i = blockIdx.x * 256 + threadIdx.x;
    if (i < n) d[i] = a[i] + b[i];
}
__global__ void zeroh_k(u16* h0, u16* h1) {   // n = 256*1024
    int i = blockIdx.x * 256 + threadIdx.x;
    h0[i] = 0; h1[i] = 0;
}
__global__ void pack_enc_k(const float* __restrict__ pre_x, const float* __restrict__ pre_y,
                           u16* __restrict__ xy) {   // threads = 64*16*8*64
    int i = blockIdx.x * 256 + threadIdx.x;
    const int lane  = i & 63;
    const int kb    = (i >> 6) & 7;
    const int mtile = (i >> 9) & 15;
    const int t     = i >> 13;
    const int row   = mtile * 16 + (lane & 15);
    const int cb    = kb * 32 + (lane >> 4) * 8;
    u16* d = xy + (size_t)i * 8;
    #pragma unroll
    for (int j = 0; j < 8; ++j) {
        const int col = cb + j;
        const float v = (col < 192) ? pre_x[((size_t)t * 256 + row) * 192 + col]
                                    : pre_y[((size_t)t * 256 + row) * 64 + (col - 192)];
        d[j] = f2h(v);
    }
}
__global__ void pack_dec_k(const float* __restrict__ fx, u16* __restrict__ xd,
                           int total_threads) {      // threads = 48*16*6*64
    int i = blockIdx.x * 256 + threadIdx.x;
    if (i >= total_threads) return;
    const int lane  = i & 63;
    int rest = i >> 6;
    const int kb    = rest % 6;  rest /= 6;
    const int mtile = rest & 15;
    const int t     = rest >> 4;
    const int row   = mtile * 16 + (lane & 15);
    const int cb    = kb * 32 + (lane >> 4) * 8;
    u16* d = xd + ((((size_t)t * 16 + mtile) * 8 + kb) * 64 + lane) * 8;
    #pragma unroll
    for (int j = 0; j < 8; ++j)
        d[j] = f2h(fx[((size_t)t * 256 + row) * 192 + cb + j]);
}

extern "C" void kernel_launch(void* const* d_in, const int* in_sizes, int n_in,
                              void* d_out, int out_size, void* d_ws, size_t ws_size,
                              hipStream_t stream) {
    const float* pre_x  = (const float*)d_in[0];
    const float* pre_y  = (const float*)d_in[1];
    const float* fx     = (const float*)d_in[2];
    const float* w_ih_0 = (const float*)d_in[3];
    const float* w_hh_0 = (const float*)d_in[4];
    const float* b_ih_0 = (const float*)d_in[5];
    const float* b_hh_0 = (const float*)d_in[6];
    const float* w_ih_1 = (const float*)d_in[7];
    const float* w_hh_1 = (const float*)d_in[8];
    const float* b_ih_1 = (const float*)d_in[9];
    const float* b_hh_1 = (const float*)d_in[10];
    const float* fc_w1  = (const float*)d_in[11];
    const float* fc_b1  = (const float*)d_in[12];
    const float* fc_w2  = (const float*)d_in[13];
    const float* fc_b2  = (const float*)d_in[14];

    size_t off = 0;
    char* wsb = (char*)d_ws;
    auto alloc = [&](size_t bytes) -> void* {
        void* p = wsb + off;
        off += (bytes + 255) & ~(size_t)255;
        return p;
    };
    u16* wih0 = (u16*)alloc((size_t)4096 * 256 * 2);
    u16* whh0 = (u16*)alloc((size_t)4096 * 1024 * 2);
    u16* wih1 = (u16*)alloc((size_t)4096 * 1024 * 2);
    u16* whh1 = (u16*)alloc((size_t)4096 * 1024 * 2);
    u16* fcw1 = (u16*)alloc((size_t)1024 * 1024 * 2);
    u16* fcw2 = (u16*)alloc((size_t)64 * 1024 * 2);
    float* b0s = (float*)alloc(4096 * 4);
    float* b1s = (float*)alloc(4096 * 4);
    u16* xyenc = (u16*)alloc((size_t)64 * 256 * 256 * 2);
    u16* xdec  = (u16*)alloc((size_t)48 * 256 * 256 * 2);
    u16* h0a = (u16*)alloc((size_t)256 * 1024 * 2);
    u16* h0b = (u16*)alloc((size_t)256 * 1024 * 2);
    u16* h1a = (u16*)alloc((size_t)256 * 1024 * 2);
    u16* h1b = (u16*)alloc((size_t)256 * 1024 * 2);
    u16* ufc = (u16*)alloc((size_t)256 * 1024 * 2);

    // --- setup ---
    cvt_bfrag_k<<<512, 256, 0, stream>>>(w_ih_0, wih0, 256, 3, 1024, 16, 64 * 4 * 8 * 64);
    cvt_bfrag_k<<<2048, 256, 0, stream>>>(w_hh_0, whh0, 1024, 5, 1024, 16, 64 * 4 * 32 * 64);
    cvt_bfrag_k<<<2048, 256, 0, stream>>>(w_ih_1, wih1, 1024, 5, 1024, 16, 64 * 4 * 32 * 64);
    cvt_bfrag_k<<<2048, 256, 0, stream>>>(w_hh_1, whh1, 1024, 5, 1024, 16, 64 * 4 * 32 * 64);
    cvt_bfrag_k<<<512, 256, 0, stream>>>(fc_w1, fcw1, 1024, 5, 16, 64, 16 * 4 * 32 * 64);
    cvt_bfrag_k<<<32, 256, 0, stream>>>(fc_w2, fcw2, 1024, 5, 16, 0, 1 * 4 * 32 * 64);
    bias_k<<<16, 256, 0, stream>>>(b_ih_0, b_hh_0, b0s, 4096);
    bias_k<<<16, 256, 0, stream>>>(b_ih_1, b_hh_1, b1s, 4096);
    zeroh_k<<<1024, 256, 0, stream>>>(h0a, h1a);
    pack_enc_k<<<2048, 256, 0, stream>>>(pre_x, pre_y, xyenc);
    pack_dec_k<<<1152, 256, 0, stream>>>(fx, xdec, 48 * 16 * 6 * 64);

    // --- persistent recurrence ---
    PP p;
    p.xyenc = xyenc; p.xdec = xdec;
    p.wih0 = wih0; p.whh0 = whh0; p.wih1 = wih1; p.whh1 = whh1;
    p.fcw1 = fcw1; p.fcw2 = fcw2;
    p.b0s = b0s; p.b1s = b1s; p.fcb1 = fc_b1; p.fcb2 = fc_b2; p.pre_y = pre_y;
    p.h0a = h0a; p.h0b = h0b; p.h1a = h1a; p.h1b = h1b; p.ufc = ufc;
    p.out = (float*)d_out;

    void* args[] = { &p };
    hipLaunchCooperativeKernel((const void*)persist_k, dim3(256), dim3(512),
                               args, 0, stream);
}

// Round 4
// 3861.045 us; speedup vs baseline: 3.1003x; 3.1003x over previous
//
#include <hip/hip_runtime.h>
#include <stdint.h>

typedef unsigned short u16;
typedef __attribute__((ext_vector_type(8))) _Float16 f16x8;
typedef __attribute__((ext_vector_type(4))) float f32x4;

// ---------- helpers ----------
__device__ inline f16x8 ldfrag(const u16* p) { return *(const f16x8*)p; }

// device-scope (cross-XCD coherent) 16B load: bypasses L2, served by L3.
__device__ __forceinline__ f16x8 ldfrag_dc(const u16* p) {
    f16x8 r;
    asm volatile("global_load_dwordx4 %0, %1, off sc1" : "=&v"(r) : "v"(p));
    return r;
}
// device-scope scalar u16 store
__device__ __forceinline__ void st_u16_dc(u16* p, u16 v) {
    unsigned vv = v;
    asm volatile("global_store_short %0, %1, off sc1" :: "v"(p), "v"(vv) : "memory");
}
// drain vmem then fence the scheduler so MFMAs can't hoist above (rule #18)
__device__ __forceinline__ void wait_vm0() {
    asm volatile("s_waitcnt vmcnt(0)" ::: "memory");
    __builtin_amdgcn_sched_barrier(0);
}

__device__ inline u16 f2h(float x) {
    _Float16 h = (_Float16)x;
    union { _Float16 h; u16 u; } v; v.h = h;
    return v.u;
}
__device__ inline float sigmoidf_(float x) { return 1.0f / (1.0f + expf(-x)); }

// custom grid barrier: monotonic counter + release word, relaxed agent atomics.
// No release/acquire fences -> no buffer_wbl2/buffer_inv -> L2 stays warm.
// Visibility of activation data is handled by sc1 loads/stores at the call sites.
__device__ __forceinline__ void gbar(unsigned* cnt, unsigned* rel, unsigned ep) {
    __syncthreads();   // drains all waves' vmem (stores acked at coherence point)
    if (threadIdx.x == 0) {
        unsigned old = __hip_atomic_fetch_add(cnt, 1u, __ATOMIC_RELAXED,
                                              __HIP_MEMORY_SCOPE_AGENT);
        if (old == ep * 256u + 255u) {
            __hip_atomic_store(rel, ep + 1u, __ATOMIC_RELAXED,
                               __HIP_MEMORY_SCOPE_AGENT);
        } else {
            unsigned r;
            do {
                __builtin_amdgcn_s_sleep(8);
                r = __hip_atomic_load(rel, __ATOMIC_RELAXED,
                                      __HIP_MEMORY_SCOPE_AGENT);
            } while (r < ep + 1u);
        }
    }
    __syncthreads();
    asm volatile("" ::: "memory");
}

// Layouts (fp16 as u16):
//  A-frag (X: 256 x K):  AF[mtile][kb][lane][8]
//      = X[mtile*16 + (lane&15)][kb*32 + (lane>>4)*8 + j]
//  B-frag (W: N x K):    BF[grp][sub][kb][lane][8]
//      = W[row(grp,sub,lane)][kb*32 + (lane>>4)*8 + j],  row = sub*S1 + grp*S2 + (lane&15)
//  lstm:  S1=1024 (gate), S2=16 (ct)   -> BF[ct][gate][kb][..]
//  fc1:   S1=16,  S2=64                -> BF[ctq][nt ][kb][..]
//  fc2:   S1=16,  S2=0 (grp=0)         -> BF[0][nt][kb][..]

struct PP {
    const u16* xyenc;
    u16* xdec;
    const u16 *wih0, *whh0, *wih1, *whh1, *fcw1, *fcw2;
    const float *b0s, *b1s, *fcb1, *fcb2, *pre_y;
    u16 *h0a, *h0b, *h1a, *h1b, *ufc;
    float* out;
    unsigned *cnt, *rel;
};

// ---------- LSTM cell phase (per-block role: ct = b&63, mg = b>>6) ----------
// 512 threads = 8 waves, 8-way K-split; two-stage LDS reduction; c-state in regs.
// adyn: AFa is dynamic (written during this kernel) -> needs sc1 loads.
// AFh is always dynamic (h state).
static __device__ __forceinline__ void lstm_phase(
    const u16* __restrict__ AFa, int KBa, bool adyn, const u16* __restrict__ BFa,
    const u16* __restrict__ AFh, const u16* __restrict__ BFh,
    const float* __restrict__ bsum, float* creg, u16* __restrict__ h_out,
    int ct, int mg, int w, int lane, f32x4 (*red)[16][64])
{
    const int l15  = lane & 15;
    const int quad = lane >> 4;

    f32x4 acc[4][4];
    #pragma unroll
    for (int t = 0; t < 4; ++t)
        #pragma unroll
        for (int g = 0; g < 4; ++g) acc[t][g] = (f32x4){0, 0, 0, 0};

    // phase A: x-side, wave w takes kb in [w*q, w*q+q), q = KBa/8
    {
        const int q = KBa >> 3;
        for (int kb = w * q; kb < w * q + q; ++kb) {
            f16x8 a[4], b[4];
            if (adyn) {
                #pragma unroll
                for (int t = 0; t < 4; ++t)
                    a[t] = ldfrag_dc(AFa + (((size_t)(mg * 4 + t) * KBa + kb) * 64 + lane) * 8);
            } else {
                #pragma unroll
                for (int t = 0; t < 4; ++t)
                    a[t] = ldfrag(AFa + (((size_t)(mg * 4 + t) * KBa + kb) * 64 + lane) * 8);
            }
            #pragma unroll
            for (int g = 0; g < 4; ++g)
                b[g] = ldfrag(BFa + (((size_t)(ct * 4 + g) * KBa + kb) * 64 + lane) * 8);
            wait_vm0();
            #pragma unroll
            for (int t = 0; t < 4; ++t)
                #pragma unroll
                for (int g = 0; g < 4; ++g)
                    acc[t][g] = __builtin_amdgcn_mfma_f32_16x16x32_f16(a[t], b[g], acc[t][g], 0, 0, 0);
        }
    }
    // phase B: h-side, KB=32, eighth = 4 (h is always dynamic -> sc1)
    {
        #pragma unroll 2
        for (int kb = w * 4; kb < w * 4 + 4; ++kb) {
            f16x8 a[4], b[4];
            #pragma unroll
            for (int t = 0; t < 4; ++t)
                a[t] = ldfrag_dc(AFh + (((size_t)(mg * 4 + t) * 32 + kb) * 64 + lane) * 8);
            #pragma unroll
            for (int g = 0; g < 4; ++g)
                b[g] = ldfrag(BFh + (((size_t)(ct * 4 + g) * 32 + kb) * 64 + lane) * 8);
            wait_vm0();
            #pragma unroll
            for (int t = 0; t < 4; ++t)
                #pragma unroll
                for (int g = 0; g < 4; ++g)
                    acc[t][g] = __builtin_amdgcn_mfma_f32_16x16x32_f16(a[t], b[g], acc[t][g], 0, 0, 0);
        }
    }

    // two-stage cross-wave K-reduction (8 partials -> 4 -> sum)
    if (w >= 4) {
        #pragma unroll
        for (int t = 0; t < 4; ++t)
            #pragma unroll
            for (int g = 0; g < 4; ++g)
                red[w - 4][t * 4 + g][lane] = acc[t][g];
    }
    __syncthreads();
    if (w < 4) {
        #pragma unroll
        for (int t = 0; t < 4; ++t)
            #pragma unroll
            for (int g = 0; g < 4; ++g)
                red[w][t * 4 + g][lane] += acc[t][g];
    }
    __syncthreads();
    if (w < 4) {
        // wave w owns mt = mg*4 + w
        f32x4 z[4];
        #pragma unroll
        for (int g = 0; g < 4; ++g)
            z[g] = red[0][w * 4 + g][lane] + red[1][w * 4 + g][lane] +
                   red[2][w * 4 + g][lane] + red[3][w * 4 + g][lane];

        const int col   = ct * 16 + l15;
        const int mtile = mg * 4 + w;
        float bv[4];
        #pragma unroll
        for (int g = 0; g < 4; ++g) bv[g] = bsum[g * 1024 + col];
        const int hkb = col >> 5, hquad = (col >> 3) & 3, hj = col & 7;
        #pragma unroll
        for (int r = 0; r < 4; ++r) {
            const int rl = quad * 4 + r;
            const float zi = z[0][r] + bv[0];
            const float zf = z[1][r] + bv[1];
            const float zg = z[2][r] + bv[2];
            const float zo = z[3][r] + bv[3];
            const float cv = creg[r];
            const float cn = sigmoidf_(zf) * cv + sigmoidf_(zi) * tanhf(zg);
            creg[r] = cn;
            st_u16_dc(h_out + (((size_t)mtile * 32 + hkb) * 64 + hquad * 16 + rl) * 8 + hj,
                      f2h(sigmoidf_(zo) * tanhf(cn)));
        }
    }
}

// ---------- FC1 phase: U = tanh(h1 @ fc_w1^T + b1) ----------
// 256 blocks: mt = b>>4 (0..15), ctq = b&15; 8 waves 8-way K-split.
static __device__ __forceinline__ void fc1_phase(
    const u16* __restrict__ AFx, const u16* __restrict__ BFw,
    const float* __restrict__ bias, u16* __restrict__ U,
    int b, int w, int lane, f32x4 (*red)[16][64])
{
    const int mt = b >> 4, ctq = b & 15;
    const int l15 = lane & 15, quad = lane >> 4;
    f32x4 acc[4];
    #pragma unroll
    for (int g = 0; g < 4; ++g) acc[g] = (f32x4){0, 0, 0, 0};

    #pragma unroll
    for (int k = 0; k < 4; ++k) {
        const int kb = w * 4 + k;
        f16x8 a = ldfrag_dc(AFx + (((size_t)mt * 32 + kb) * 64 + lane) * 8);
        f16x8 bb[4];
        #pragma unroll
        for (int g = 0; g < 4; ++g)
            bb[g] = ldfrag(BFw + (((size_t)(ctq * 4 + g) * 32 + kb) * 64 + lane) * 8);
        wait_vm0();
        #pragma unroll
        for (int g = 0; g < 4; ++g)
            acc[g] = __builtin_amdgcn_mfma_f32_16x16x32_f16(a, bb[g], acc[g], 0, 0, 0);
    }

    f32x4 (*r8)[4][64] = (f32x4 (*)[4][64])red;   // [8][4][64]
    #pragma unroll
    for (int g = 0; g < 4; ++g) r8[w][g][lane] = acc[g];
    __syncthreads();
    if (w < 4) {
        f32x4 z = r8[0][w][lane];
        #pragma unroll
        for (int p = 1; p < 8; ++p) z += r8[p][w][lane];
        const int col = ctq * 64 + w * 16 + l15;
        const float bv = bias[col];
        const int ukb = col >> 5, uq = (col >> 3) & 3, uj = col & 7;
        #pragma unroll
        for (int r = 0; r < 4; ++r) {
            const int rl = quad * 4 + r;
            st_u16_dc(U + (((size_t)mt * 32 + ukb) * 64 + uq * 16 + rl) * 8 + uj,
                      f2h(tanhf(z[r] + bv)));
        }
    }
}

// ---------- FC2 phase + est feedback (blocks b<64: mt = b>>2, cg = b&3) ----------
static __device__ __forceinline__ void fc2_phase(
    const u16* __restrict__ AFu, const u16* __restrict__ BFw2,
    const float* __restrict__ b2, float* estreg,
    float* __restrict__ out_t, u16* __restrict__ xdec_t,
    int b, int w, int lane, f32x4 (*red)[16][64])
{
    f32x4 (*rr)[64] = (f32x4 (*)[64])red;   // [8][64]
    const int l15 = lane & 15, quad = lane >> 4;
    const int mt = b >> 2, cg = b & 3;
    if (b < 64) {
        f32x4 acc = (f32x4){0, 0, 0, 0};
        #pragma unroll
        for (int k = 0; k < 4; ++k) {
            const int kb = w * 4 + k;
            f16x8 a = ldfrag_dc(AFu + (((size_t)mt * 32 + kb) * 64 + lane) * 8);
            f16x8 bb = ldfrag(BFw2 + (((size_t)cg * 32 + kb) * 64 + lane) * 8);
            wait_vm0();
            acc = __builtin_amdgcn_mfma_f32_16x16x32_f16(a, bb, acc, 0, 0, 0);
        }
        rr[w][lane] = acc;
    }
    __syncthreads();
    if (b < 64 && w == 0) {
        f32x4 acc = rr[0][lane];
        #pragma unroll
        for (int p = 1; p < 8; ++p) acc += rr[p][lane];
        const int col = cg * 16 + l15;
        const float bv = b2[col];
        const int cx = 192 + col;
        const int xkb = cx >> 5, xq = (cx >> 3) & 3, xj = cx & 7;
        #pragma unroll
        for (int r = 0; r < 4; ++r) {
            const int rl = quad * 4 + r;
            const int row = mt * 16 + rl;
            const float v = acc[r] + bv + estreg[r];
            estreg[r] = v;
            out_t[row * 64 + col] = v;   // host-visible only; plain store
            st_u16_dc(xdec_t + (((size_t)mt * 8 + xkb) * 64 + xq * 16 + rl) * 8 + xj, f2h(v));
        }
    }
}

// ---------- persistent kernel: whole recurrence, custom barrier ----------
__global__ __launch_bounds__(512, 2) void persist_k(PP p)
{
    __shared__ f32x4 red[4][16][64];   // 64 KB, reused by every phase

    const int tid  = threadIdx.x;
    const int w    = tid >> 6;
    const int lane = tid & 63;
    const int l15  = lane & 15;
    const int quad = lane >> 4;
    const int b    = blockIdx.x;       // 0..255
    const int ct   = b & 63;
    const int mg   = b >> 6;

    unsigned ep = 0;

    // persistent per-thread state
    float c0reg[4] = {0.f, 0.f, 0.f, 0.f};
    float c1reg[4] = {0.f, 0.f, 0.f, 0.f};
    float estreg[4] = {0.f, 0.f, 0.f, 0.f};
    if (b < 64) {   // only fc2-active blocks own est state
        const int fmt = b >> 2, fcg = b & 3;
        #pragma unroll
        for (int r = 0; r < 4; ++r) {
            const int row = fmt * 16 + quad * 4 + r;
            const int col = fcg * 16 + l15;
            estreg[r] = p.pre_y[(size_t)63 * 16384 + row * 64 + col];  // pre_y[-1]
        }
    }

    u16 *h0c = p.h0a, *h0n = p.h0b;
    u16 *h1c = p.h1a, *h1n = p.h1b;

    // --- encode: 64 steps, 2 barriers each ---
    for (int t = 0; t < 64; ++t) {
        lstm_phase(p.xyenc + (size_t)t * 65536, 8, false, p.wih0, h0c, p.whh0,
                   p.b0s, c0reg, h0n, ct, mg, w, lane, red);
        gbar(p.cnt, p.rel, ep); ++ep;
        lstm_phase(h0n, 32, true, p.wih1, h1c, p.whh1,
                   p.b1s, c1reg, h1n, ct, mg, w, lane, red);
        gbar(p.cnt, p.rel, ep); ++ep;
        u16* tmp;
        tmp = h0c; h0c = h0n; h0n = tmp;
        tmp = h1c; h1c = h1n; h1n = tmp;
    }

    // --- decode: 48 steps; last step needs only fc1+fc2 ---
    for (int t = 0; t < 48; ++t) {
        fc1_phase(h1c, p.fcw1, p.fcb1, p.ufc, b, w, lane, red);
        gbar(p.cnt, p.rel, ep); ++ep;
        fc2_phase(p.ufc, p.fcw2, p.fcb2, estreg,
                  p.out + (size_t)t * 16384, p.xdec + (size_t)t * 65536,
                  b, w, lane, red);
        gbar(p.cnt, p.rel, ep); ++ep;
        if (t < 47) {
            lstm_phase(p.xdec + (size_t)t * 65536, 8, true, p.wih0, h0c, p.whh0,
                       p.b0s, c0reg, h0n, ct, mg, w, lane, red);
            gbar(p.cnt, p.rel, ep); ++ep;
            lstm_phase(h0n, 32, true, p.wih1, h1c, p.whh1,
                       p.b1s, c1reg, h1n, ct, mg, w, lane, red);
            gbar(p.cnt, p.rel, ep); ++ep;
            u16* tmp;
            tmp = h0c; h0c = h0n; h0n = tmp;
            tmp = h1c; h1c = h1n; h1n = tmp;
        }
    }
}

// ---------- setup kernels ----------
__global__ void cvt_bfrag_k(const float* __restrict__ src, u16* __restrict__ dst,
                            int K, int kbshift, int S1, int S2, int total) {
    int i = blockIdx.x * 256 + threadIdx.x;
    if (i >= total) return;
    const int lane = i & 63;
    const int kb   = (i >> 6) & ((1 << kbshift) - 1);
    const int rest = i >> (6 + kbshift);
    const int sub  = rest & 3;
    const int grp  = rest >> 2;
    const int row  = sub * S1 + grp * S2 + (lane & 15);
    const int colK = kb * 32 + (lane >> 4) * 8;
    const float* s = src + (size_t)row * K + colK;
    u16* d = dst + (size_t)i * 8;
    #pragma unroll
    for (int j = 0; j < 8; ++j) d[j] = f2h(s[j]);
}
__global__ void bias_k(const float* __restrict__ a, const float* __restrict__ b,
                       float* __restrict__ d, int n) {
    int i = blockIdx.x * 256 + threadIdx.x;
    if (i < n) d[i] = a[i] + b[i];
}
__global__ void zeroh_k(u16* h0, u16* h1, unsigned* bar) {   // n = 256*1024
    int i = blockIdx.x * 256 + threadIdx.x;
    h0[i] = 0; h1[i] = 0;
    if (i < 128) bar[i] = 0u;
}
__global__ void pack_enc_k(const float* __restrict__ pre_x, const float* __restrict__ pre_y,
                           u16* __restrict__ xy) {   // threads = 64*16*8*64
    int i = blockIdx.x * 256 + threadIdx.x;
    const int lane  = i & 63;
    const int kb    = (i >> 6) & 7;
    const int mtile = (i >> 9) & 15;
    const int t     = i >> 13;
    const int row   = mtile * 16 + (lane & 15);
    const int cb    = kb * 32 + (lane >> 4) * 8;
    u16* d = xy + (size_t)i * 8;
    #pragma unroll
    for (int j = 0; j < 8; ++j) {
        const int col = cb + j;
        const float v = (col < 192) ? pre_x[((size_t)t * 256 + row) * 192 + col]
                                    : pre_y[((size_t)t * 256 + row) * 64 + (col - 192)];
        d[j] = f2h(v);
    }
}
__global__ void pack_dec_k(const float* __restrict__ fx, u16* __restrict__ xd,
                           int total_threads) {      // threads = 48*16*6*64
    int i = blockIdx.x * 256 + threadIdx.x;
    if (i >= total_threads) return;
    const int lane  = i & 63;
    int rest = i >> 6;
    const int kb    = rest % 6;  rest /= 6;
    const int mtile = rest & 15;
    const int t     = rest >> 4;
    const int row   = mtile * 16 + (lane & 15);
    const int cb    = kb * 32 + (lane >> 4) * 8;
    u16* d = xd + ((((size_t)t * 16 + mtile) * 8 + kb) * 64 + lane) * 8;
    #pragma unroll
    for (int j = 0; j < 8; ++j)
        d[j] = f2h(fx[((size_t)t * 256 + row) * 192 + cb + j]);
}

extern "C" void kernel_launch(void* const* d_in, const int* in_sizes, int n_in,
                              void* d_out, int out_size, void* d_ws, size_t ws_size,
                              hipStream_t stream) {
    const float* pre_x  = (const float*)d_in[0];
    const float* pre_y  = (const float*)d_in[1];
    const float* fx     = (const float*)d_in[2];
    const float* w_ih_0 = (const float*)d_in[3];
    const float* w_hh_0 = (const float*)d_in[4];
    const float* b_ih_0 = (const float*)d_in[5];
    const float* b_hh_0 = (const float*)d_in[6];
    const float* w_ih_1 = (const float*)d_in[7];
    const float* w_hh_1 = (const float*)d_in[8];
    const float* b_ih_1 = (const float*)d_in[9];
    const float* b_hh_1 = (const float*)d_in[10];
    const float* fc_w1  = (const float*)d_in[11];
    const float* fc_b1  = (const float*)d_in[12];
    const float* fc_w2  = (const float*)d_in[13];
    const float* fc_b2  = (const float*)d_in[14];

    size_t off = 0;
    char* wsb = (char*)d_ws;
    auto alloc = [&](size_t bytes) -> void* {
        void* p = wsb + off;
        off += (bytes + 255) & ~(size_t)255;
        return p;
    };
    u16* wih0 = (u16*)alloc((size_t)4096 * 256 * 2);
    u16* whh0 = (u16*)alloc((size_t)4096 * 1024 * 2);
    u16* wih1 = (u16*)alloc((size_t)4096 * 1024 * 2);
    u16* whh1 = (u16*)alloc((size_t)4096 * 1024 * 2);
    u16* fcw1 = (u16*)alloc((size_t)1024 * 1024 * 2);
    u16* fcw2 = (u16*)alloc((size_t)64 * 1024 * 2);
    float* b0s = (float*)alloc(4096 * 4);
    float* b1s = (float*)alloc(4096 * 4);
    u16* xyenc = (u16*)alloc((size_t)64 * 256 * 256 * 2);
    u16* xdec  = (u16*)alloc((size_t)48 * 256 * 256 * 2);
    u16* h0a = (u16*)alloc((size_t)256 * 1024 * 2);
    u16* h0b = (u16*)alloc((size_t)256 * 1024 * 2);
    u16* h1a = (u16*)alloc((size_t)256 * 1024 * 2);
    u16* h1b = (u16*)alloc((size_t)256 * 1024 * 2);
    u16* ufc = (u16*)alloc((size_t)256 * 1024 * 2);
    unsigned* bar = (unsigned*)alloc(512);

    // --- setup ---
    cvt_bfrag_k<<<512, 256, 0, stream>>>(w_ih_0, wih0, 256, 3, 1024, 16, 64 * 4 * 8 * 64);
    cvt_bfrag_k<<<2048, 256, 0, stream>>>(w_hh_0, whh0, 1024, 5, 1024, 16, 64 * 4 * 32 * 64);
    cvt_bfrag_k<<<2048, 256, 0, stream>>>(w_ih_1, wih1, 1024, 5, 1024, 16, 64 * 4 * 32 * 64);
    cvt_bfrag_k<<<2048, 256, 0, stream>>>(w_hh_1, whh1, 1024, 5, 1024, 16, 64 * 4 * 32 * 64);
    cvt_bfrag_k<<<512, 256, 0, stream>>>(fc_w1, fcw1, 1024, 5, 16, 64, 16 * 4 * 32 * 64);
    cvt_bfrag_k<<<32, 256, 0, stream>>>(fc_w2, fcw2, 1024, 5, 16, 0, 1 * 4 * 32 * 64);
    bias_k<<<16, 256, 0, stream>>>(b_ih_0, b_hh_0, b0s, 4096);
    bias_k<<<16, 256, 0, stream>>>(b_ih_1, b_hh_1, b1s, 4096);
    zeroh_k<<<1024, 256, 0, stream>>>(h0a, h1a, bar);
    pack_enc_k<<<2048, 256, 0, stream>>>(pre_x, pre_y, xyenc);
    pack_dec_k<<<1152, 256, 0, stream>>>(fx, xdec, 48 * 16 * 6 * 64);

    // --- persistent recurrence ---
    PP p;
    p.xyenc = xyenc; p.xdec = xdec;
    p.wih0 = wih0; p.whh0 = whh0; p.wih1 = wih1; p.whh1 = whh1;
    p.fcw1 = fcw1; p.fcw2 = fcw2;
    p.b0s = b0s; p.b1s = b1s; p.fcb1 = fc_b1; p.fcb2 = fc_b2; p.pre_y = pre_y;
    p.h0a = h0a; p.h0b = h0b; p.h1a = h1a; p.h1b = h1b; p.ufc = ufc;
    p.out = (float*)d_out;
    p.cnt = bar; p.rel = bar + 64;

    void* args[] = { &p };
    hipLaunchCooperativeKernel((const void*)persist_k, dim3(256), dim3(512),
                               args, 0, stream);
}